// Round 4
// baseline (1240.174 us; speedup 1.0000x reference)
//
#include <hip/hip_runtime.h>
#include <cstdint>
#include <cstddef>

typedef _Float16 F16;
typedef _Float16 f16x8 __attribute__((ext_vector_type(8)));
typedef float f32x4 __attribute__((ext_vector_type(4)));

#define ASYNC_COPY16(gsrc, ldst)                                                        \
  __builtin_amdgcn_global_load_lds((const __attribute__((address_space(1))) void*)(gsrc), \
                                   (__attribute__((address_space(3))) void*)(ldst), 16, 0, 0)

// ---------------------------------------------------------------------------
// Batched cast fp32 -> f16: one launch for (nearly) all weight casts.
constexpr int NCAST = 11;
struct CastJobs {
  const float* src[NCAST];
  F16* dst[NCAST];
  int nblk[NCAST];  // blocks per job; each block casts 2048 elems
};

__global__ __launch_bounds__(256) void cast_many(CastJobs j) {
  int rem = blockIdx.x;
  const float* src = j.src[0];
  F16* dst = j.dst[0];
  bool found = false;
#pragma unroll
  for (int s = 0; s < NCAST; ++s) {
    bool here = !found && (rem < j.nblk[s]);
    if (here) { src = j.src[s]; dst = j.dst[s]; found = true; }
    if (!found) rem -= j.nblk[s];
  }
  size_t i = ((size_t)rem * 256 + threadIdx.x) * 8;
  float4 a = *(const float4*)&src[i];
  float4 b = *(const float4*)&src[i + 4];
  f16x8 o;
  o[0] = (F16)a.x; o[1] = (F16)a.y; o[2] = (F16)a.z; o[3] = (F16)a.w;
  o[4] = (F16)b.x; o[5] = (F16)b.y; o[6] = (F16)b.z; o[7] = (F16)b.w;
  *(f16x8*)&dst[i] = o;
}

// Single-source cast (used for per-pass W2 cast in the smallest ws tier)
__global__ __launch_bounds__(256) void cast_one(const float* __restrict__ in,
                                                F16* __restrict__ out) {
  size_t i = ((size_t)blockIdx.x * 256 + threadIdx.x) * 8;
  float4 a = *(const float4*)&in[i];
  float4 b = *(const float4*)&in[i + 4];
  f16x8 o;
  o[0] = (F16)a.x; o[1] = (F16)a.y; o[2] = (F16)a.z; o[3] = (F16)a.w;
  o[4] = (F16)b.x; o[5] = (F16)b.y; o[6] = (F16)b.z; o[7] = (F16)b.w;
  *(f16x8*)&out[i] = o;
}

// Cast feat [2048,512] f32 into first 512 cols of fi/ft [2048,1024] f16
__global__ __launch_bounds__(256) void cast_half_cols(const float* __restrict__ src_i,
                                                      const float* __restrict__ src_t,
                                                      F16* __restrict__ fi, F16* __restrict__ ft) {
  int mod = blockIdx.z;
  const float* in = mod ? src_t : src_i;
  F16* out = mod ? ft : fi;
  int t = blockIdx.x * 256 + threadIdx.x;  // 131072 total
  int i = t * 8;
  int row = i >> 9, c = i & 511;
  float4 a = *(const float4*)&in[(size_t)row * 512 + c];
  float4 b = *(const float4*)&in[(size_t)row * 512 + c + 4];
  f16x8 o;
  o[0] = (F16)a.x; o[1] = (F16)a.y; o[2] = (F16)a.z; o[3] = (F16)a.w;
  o[4] = (F16)b.x; o[5] = (F16)b.y; o[6] = (F16)b.z; o[7] = (F16)b.w;
  *(f16x8*)&out[(size_t)row * 1024 + c] = o;
}

// ---------------------------------------------------------------------------
// fp32 partial argmax. grid (2048/64, 4096/128, 2), block 256.
// Block: 64 rows x 128 prompts. Thread: 4 rows (4ty..4ty+3) x 8 cols (16j+tx).
__global__ __launch_bounds__(256) void argmax_part(const float* __restrict__ feat_i,
                                                   const float* __restrict__ feat_t,
                                                   const float* __restrict__ prompts,
                                                   float* __restrict__ pval, int* __restrict__ pidx) {
  const int mod = blockIdx.z;
  const float* feat = mod ? feat_t : feat_i;
  const int r0 = blockIdx.x * 64;
  const int p0 = blockIdx.y * 128;
  const int tid = threadIdx.x;
  const int tx = tid & 15, ty = tid >> 4;
  __shared__ __align__(16) float sA[64][36];
  __shared__ __align__(16) float sB[128][36];
  float acc[4][8] = {};
  for (int kt = 0; kt < 512; kt += 32) {
#pragma unroll
    for (int i = 0; i < 2; ++i) {
      int t = tid + 256 * i;
      int row = t >> 3, c = (t & 7) * 4;
      *(float4*)&sA[row][c] = *(const float4*)&feat[(size_t)(r0 + row) * 512 + kt + c];
    }
#pragma unroll
    for (int i = 0; i < 4; ++i) {
      int t = tid + 256 * i;
      int row = t >> 3, c = (t & 7) * 4;
      *(float4*)&sB[row][c] = *(const float4*)&prompts[(size_t)(p0 + row) * 512 + kt + c];
    }
    __syncthreads();
#pragma unroll
    for (int k = 0; k < 32; k += 4) {
      float4 a[4];
#pragma unroll
      for (int i = 0; i < 4; ++i) a[i] = *(const float4*)&sA[ty * 4 + i][k];
#pragma unroll
      for (int jj = 0; jj < 8; ++jj) {
        float4 b = *(const float4*)&sB[jj * 16 + tx][k];
#pragma unroll
        for (int i = 0; i < 4; ++i) {
          acc[i][jj] = fmaf(a[i].x, b.x, acc[i][jj]);
          acc[i][jj] = fmaf(a[i].y, b.y, acc[i][jj]);
          acc[i][jj] = fmaf(a[i].z, b.z, acc[i][jj]);
          acc[i][jj] = fmaf(a[i].w, b.w, acc[i][jj]);
        }
      }
    }
    __syncthreads();
  }
  // per-thread argmax over 8 cols (ascending idx -> strict > keeps first max),
  // then shuffle-merge across the 16 tx lanes sharing the same rows.
#pragma unroll
  for (int i = 0; i < 4; ++i) {
    float v = acc[i][0];
    int id = p0 + tx;
#pragma unroll
    for (int jj = 1; jj < 8; ++jj) {
      int idx = p0 + jj * 16 + tx;
      if (acc[i][jj] > v) { v = acc[i][jj]; id = idx; }
    }
#pragma unroll
    for (int off = 1; off < 16; off <<= 1) {
      float ov = __shfl_xor(v, off);
      int oi = __shfl_xor(id, off);
      if (ov > v || (ov == v && oi < id)) { v = ov; id = oi; }
    }
    if (tx == 0) {
      pval[((size_t)mod * 2048 + r0 + ty * 4 + i) * 32 + blockIdx.y] = v;
      pidx[((size_t)mod * 2048 + r0 + ty * 4 + i) * 32 + blockIdx.y] = id;
    }
  }
}

// Merge 32 partials per row (idx tiebreak = first max) + gather prompt row as f16.
// grid 1024, block 256 (wave per row)
__global__ __launch_bounds__(256) void argmax_merge_gather(const float* __restrict__ pval,
                                                           const int* __restrict__ pidx,
                                                           const F16* __restrict__ prompts_h,
                                                           F16* __restrict__ rm_i,
                                                           F16* __restrict__ rm_t) {
  int tid = threadIdx.x;
  int w = tid >> 6, lane = tid & 63;
  int rowg = blockIdx.x * 4 + w;  // 0..4095
  int mod = rowg >> 11, r = rowg & 2047;
  const float* pv = pval + ((size_t)mod * 2048 + r) * 32;
  const int* pi = pidx + ((size_t)mod * 2048 + r) * 32;
  float v = (lane < 32) ? pv[lane] : -3.4e38f;
  int id = (lane < 32) ? pi[lane] : 0x7fffffff;
#pragma unroll
  for (int off = 16; off; off >>= 1) {
    float ov = __shfl_down(v, off);
    int oi = __shfl_down(id, off);
    if (ov > v || (ov == v && oi < id)) { v = ov; id = oi; }
  }
  int bid = __shfl(id, 0);
  const F16* src = prompts_h + (size_t)bid * 512;
  F16* dst = (mod ? rm_t : rm_i) + (size_t)r * 512;
  *(f16x8*)(dst + lane * 8) = *(const f16x8*)(src + lane * 8);
}

// ---------------------------------------------------------------------------
// m97-style f16 NT GEMM: D[z] = act(A[z] @ B[z]^T + bias[z])
// A [M,K] row-major (lda), B [N,K] row-major (ldb), per-z pointer batch.
// L2N=1 (requires BM=BN=64): fused row-l2norm epilogue, writes f32 [M,64].
struct Ptrs8 {
  const F16* A[8];
  const F16* B[8];
  const float* bias[8];
  void* D[8];
};

template <int BM, int BN, int WM, int WN, int ACT, int OUTF32, int L2N = 0>
__global__ __launch_bounds__(256) void gemm_nt(Ptrs8 p, int K, int lda, int ldb, int ldd) {
  constexpr int SM = BM / WM, SN = BN / WN;
  constexpr int FM = SM / 16, FN = SN / 16;
  __shared__ __align__(16) F16 sA[BM * 32];
  __shared__ __align__(16) F16 sB[BN * 32];
  const int tid = threadIdx.x;
  const int lane = tid & 63, wid = tid >> 6;
  const int wr = wid / WN, wc = wid % WN;
  const int z = blockIdx.z;
  const F16* A = p.A[z] + (size_t)blockIdx.x * BM * lda;
  const F16* B = p.B[z] + (size_t)blockIdx.y * BN * ldb;

  f32x4 acc[FM][FN] = {};

  const int kfrag = (lane >> 4) * 8;
  const int rA = wr * SM + (lane & 15);
  const int rB = wc * SN + (lane & 15);

  for (int kt = 0; kt < K; kt += 32) {
#pragma unroll
    for (int i = 0; i < (BM * 4) / 256; ++i) {
      int t = tid + 256 * i;
      int row = t >> 2, c = t & 3;
      ASYNC_COPY16(A + (size_t)row * lda + kt + c * 8, sA + t * 8);
    }
#pragma unroll
    for (int i = 0; i < (BN * 4) / 256; ++i) {
      int t = tid + 256 * i;
      int row = t >> 2, c = t & 3;
      ASYNC_COPY16(B + (size_t)row * ldb + kt + c * 8, sB + t * 8);
    }
    __syncthreads();
    f16x8 af[FM], bf[FN];
#pragma unroll
    for (int m = 0; m < FM; ++m) af[m] = *(const f16x8*)&sA[(rA + m * 16) * 32 + kfrag];
#pragma unroll
    for (int n = 0; n < FN; ++n) bf[n] = *(const f16x8*)&sB[(rB + n * 16) * 32 + kfrag];
#pragma unroll
    for (int m = 0; m < FM; ++m)
#pragma unroll
      for (int n = 0; n < FN; ++n)
        acc[m][n] = __builtin_amdgcn_mfma_f32_16x16x32_f16(af[m], bf[n], acc[m][n], 0, 0, 0);
    __syncthreads();
  }

  const float* bias = p.bias[z];
  if constexpr (L2N) {
    // full output row (64 cols) lives in this block: stage to LDS, row-l2norm, store f32.
    __shared__ float sOut[64][68];
#pragma unroll
    for (int m = 0; m < FM; ++m)
#pragma unroll
      for (int n = 0; n < FN; ++n) {
        int c = wc * SN + n * 16 + (lane & 15);
        float bv = bias[c];
#pragma unroll
        for (int jj = 0; jj < 4; ++jj) {
          int r = wr * SM + m * 16 + (lane >> 4) * 4 + jj;
          sOut[r][c] = acc[m][n][jj] + bv;
        }
      }
    __syncthreads();
    int row = tid >> 2, q = tid & 3;
    float4 xv[4];
    float s = 0.f;
#pragma unroll
    for (int c4 = 0; c4 < 4; ++c4) {
      xv[c4] = *(const float4*)&sOut[row][q * 16 + c4 * 4];
      s += xv[c4].x * xv[c4].x + xv[c4].y * xv[c4].y + xv[c4].z * xv[c4].z + xv[c4].w * xv[c4].w;
    }
    s += __shfl_xor(s, 1);
    s += __shfl_xor(s, 2);
    float inv = 1.f / fmaxf(sqrtf(s), 1e-12f);
    float* D = (float*)p.D[z] + (size_t)(blockIdx.x * BM + row) * 64 + q * 16;
#pragma unroll
    for (int c4 = 0; c4 < 4; ++c4) {
      float4 o;
      o.x = xv[c4].x * inv; o.y = xv[c4].y * inv; o.z = xv[c4].z * inv; o.w = xv[c4].w * inv;
      *(float4*)&D[c4 * 4] = o;
    }
  } else {
    const int m0 = blockIdx.x * BM + wr * SM, n0 = blockIdx.y * BN + wc * SN;
#pragma unroll
    for (int m = 0; m < FM; ++m) {
#pragma unroll
      for (int n = 0; n < FN; ++n) {
        int col = n0 + n * 16 + (lane & 15);
        float bv = bias ? bias[col] : 0.f;
#pragma unroll
        for (int jj = 0; jj < 4; ++jj) {
          int row = m0 + m * 16 + (lane >> 4) * 4 + jj;
          float v = acc[m][n][jj] + bv;
          if (ACT) v = fmaxf(v, 0.f);
          if (OUTF32)
            ((float*)p.D[z])[(size_t)row * ldd + col] = v;
          else
            ((F16*)p.D[z])[(size_t)row * ldd + col] = (F16)v;
        }
      }
    }
  }
}

// ---------------------------------------------------------------------------
// Row softmax (in-place, f16 rows of 2048), scale 1/8 folded into exp.
__global__ __launch_bounds__(256) void softmax_rows(F16* __restrict__ s) {
  const size_t row = blockIdx.x;
  F16* p = s + row * 2048;
  const int tid = threadIdx.x;
  const int w = tid >> 6, lane = tid & 63;
  f16x8 v8 = *(const f16x8*)(p + tid * 8);
  float v[8];
#pragma unroll
  for (int j = 0; j < 8; ++j) v[j] = (float)v8[j];
  float m = -3.4e38f;
#pragma unroll
  for (int j = 0; j < 8; ++j) m = fmaxf(m, v[j]);
#pragma unroll
  for (int off = 32; off; off >>= 1) m = fmaxf(m, __shfl_xor(m, off));
  __shared__ float red[8];
  if (lane == 0) red[w] = m;
  __syncthreads();
  m = fmaxf(fmaxf(red[0], red[1]), fmaxf(red[2], red[3]));
  float sum = 0.f;
#pragma unroll
  for (int j = 0; j < 8; ++j) {
    v[j] = __expf((v[j] - m) * 0.125f);
    sum += v[j];
  }
#pragma unroll
  for (int off = 32; off; off >>= 1) sum += __shfl_xor(sum, off);
  if (lane == 0) red[4 + w] = sum;
  __syncthreads();
  sum = red[4] + red[5] + red[6] + red[7];
  float inv = 1.f / sum;
  f16x8 o;
#pragma unroll
  for (int j = 0; j < 8; ++j) o[j] = (F16)(v[j] * inv);
  *(f16x8*)(p + tid * 8) = o;
}

// ---------------------------------------------------------------------------
// vpT[d][s] = vp[s][d]; vp = qkv cols [1024,1536). grid (2048/64, 512/64, 2)
__global__ __launch_bounds__(256) void transpose_vp(const F16* __restrict__ qkv_i,
                                                    const F16* __restrict__ qkv_t,
                                                    F16* __restrict__ vpT_i, F16* __restrict__ vpT_t) {
  int mod = blockIdx.z;
  const F16* vp = (mod ? qkv_t : qkv_i) + 1024;
  F16* vpT = mod ? vpT_t : vpT_i;
  int s0 = blockIdx.x * 64, d0 = blockIdx.y * 64;
  __shared__ __align__(16) F16 tile[64][72];
  int tid = threadIdx.x;
#pragma unroll
  for (int i = 0; i < 2; ++i) {
    int ch = tid + 256 * i;
    int row = ch >> 3, c = (ch & 7) * 8;
    *(f16x8*)&tile[row][c] = *(const f16x8*)&vp[(size_t)(s0 + row) * 1536 + d0 + c];
  }
  __syncthreads();
#pragma unroll
  for (int i = 0; i < 2; ++i) {
    int ch = tid + 256 * i;
    int dr = ch >> 3, sc = (ch & 7) * 8;
    f16x8 o;
#pragma unroll
    for (int j = 0; j < 8; ++j) o[j] = tile[sc + j][dr];
    *(f16x8*)&vpT[(size_t)(d0 + dr) * 2048 + s0 + sc] = o;
  }
}

// ---------------------------------------------------------------------------
extern "C" void kernel_launch(void* const* d_in, const int* in_sizes, int n_in, void* d_out,
                              int out_size, void* d_ws, size_t ws_size, hipStream_t stream) {
  const float* img_f = (const float*)d_in[0];
  const float* txt_f = (const float*)d_in[1];
  const float* prompts = (const float*)d_in[2];
  const float* img_in_w = (const float*)d_in[3];
  const float* img_in_b = (const float*)d_in[4];
  const float* img_out_w = (const float*)d_in[5];
  const float* img_out_b = (const float*)d_in[6];
  const float* txt_in_w = (const float*)d_in[7];
  const float* txt_in_b = (const float*)d_in[8];
  const float* txt_out_w = (const float*)d_in[9];
  const float* txt_out_b = (const float*)d_in[10];
  const float* img_W1 = (const float*)d_in[11];
  const float* img_b1 = (const float*)d_in[12];
  const float* img_W2 = (const float*)d_in[13];
  const float* img_b2 = (const float*)d_in[14];
  const float* img_Wc = (const float*)d_in[15];
  const float* img_bc = (const float*)d_in[16];
  const float* txt_W1 = (const float*)d_in[17];
  const float* txt_b1 = (const float*)d_in[18];
  const float* txt_W2 = (const float*)d_in[19];
  const float* txt_b2 = (const float*)d_in[20];
  const float* txt_Wc = (const float*)d_in[21];
  const float* txt_bc = (const float*)d_in[22];
  float* out = (float*)d_out;

  char* ws = (char*)d_ws;
  size_t off = 0;
  auto alloc = [&](size_t bytes) -> void* {
    void* p = ws + off;
    off += (bytes + 255) & ~(size_t)255;
    return p;
  };
  // ---- fixed allocations (~122 MB) ----
  F16* prompts_h = (F16*)alloc((size_t)4096 * 512 * 2);
  F16* in_w_i_h = (F16*)alloc((size_t)1536 * 512 * 2);
  F16* in_w_t_h = (F16*)alloc((size_t)1536 * 512 * 2);
  F16* out_w_i_h = (F16*)alloc((size_t)512 * 512 * 2);
  F16* out_w_t_h = (F16*)alloc((size_t)512 * 512 * 2);
  F16* W1_i = (F16*)alloc((size_t)4096 * 1024 * 2);
  F16* W1_t = (F16*)alloc((size_t)4096 * 1024 * 2);
  F16* Wc_i = (F16*)alloc((size_t)64 * 4096 * 2);
  F16* Wc_t = (F16*)alloc((size_t)64 * 4096 * 2);
  float* pval = (float*)alloc((size_t)2 * 2048 * 32 * 4);
  int* pidx = (int*)alloc((size_t)2 * 2048 * 32 * 4);
  F16* rm_i = (F16*)alloc((size_t)2048 * 512 * 2);
  F16* rm_t = (F16*)alloc((size_t)2048 * 512 * 2);
  F16* qkv_i = (F16*)alloc((size_t)2048 * 1536 * 2);
  F16* qkv_t = (F16*)alloc((size_t)2048 * 1536 * 2);
  F16* vpT_i = (F16*)alloc((size_t)512 * 2048 * 2);
  F16* vpT_t = (F16*)alloc((size_t)512 * 2048 * 2);
  F16* attn_i = (F16*)alloc((size_t)2048 * 512 * 2);
  F16* attn_t = (F16*)alloc((size_t)2048 * 512 * 2);
  F16* fi = (F16*)alloc((size_t)2048 * 1024 * 2);
  F16* ft = (F16*)alloc((size_t)2048 * 1024 * 2);
  F16* scores = (F16*)alloc((size_t)8 * 2048 * 2048 * 2);  // 64MB; reused as h1 (+h2 if tight)

  // ---- tiered allocations: W2 copies + MLP intermediate ----
  const size_t W2B = (size_t)4096 * 4096 * 2;       // 32MB each
  const size_t H2B = (size_t)4 * 2048 * 4096 * 2;   // 64MB
  F16 *W2_i = nullptr, *W2_t = nullptr, *W2_shared = nullptr, *h2full = nullptr;
  int zb;
  if (off + 2 * W2B + H2B <= ws_size) {        // tier 1 (~250MB): single 4-wide MLP pass
    W2_i = (F16*)alloc(W2B); W2_t = (F16*)alloc(W2B); h2full = (F16*)alloc(H2B); zb = 4;
  } else if (off + 2 * W2B <= ws_size) {       // tier 2 (~186MB): two 2-wide passes
    W2_i = (F16*)alloc(W2B); W2_t = (F16*)alloc(W2B); zb = 2;
  } else if (off + W2B <= ws_size) {           // tier 3 (~154MB): shared W2, cast per pass
    W2_shared = (F16*)alloc(W2B); zb = 2;
  } else {
    return;  // visible failure instead of corruption
  }

  // ---- casts (single batched launch; W2 jobs skipped in tier 3) ----
  {
    CastJobs j;
    const int w2blk = W2_i ? 8192 : 0;
    const float* srcs[NCAST] = {img_W2, txt_W2, img_W1, txt_W1, prompts,
                                img_in_w, txt_in_w, img_out_w, txt_out_w, img_Wc, txt_Wc};
    F16* dsts[NCAST] = {W2_i ? W2_i : W2_shared, W2_t ? W2_t : W2_shared, W1_i, W1_t, prompts_h,
                        in_w_i_h, in_w_t_h, out_w_i_h, out_w_t_h, Wc_i, Wc_t};
    const int nb[NCAST] = {w2blk, w2blk, 2048, 2048, 1024, 384, 384, 128, 128, 128, 128};
    int total = 0;
    for (int s = 0; s < NCAST; ++s) { j.src[s] = srcs[s]; j.dst[s] = dsts[s]; j.nblk[s] = nb[s]; total += nb[s]; }
    cast_many<<<dim3(total), 256, 0, stream>>>(j);
  }
  cast_half_cols<<<dim3(512, 1, 2), 256, 0, stream>>>(img_f, txt_f, fi, ft);

  // ---- argmax + gather (fp32) ----
  argmax_part<<<dim3(32, 32, 2), 256, 0, stream>>>(img_f, txt_f, prompts, pval, pidx);
  argmax_merge_gather<<<dim3(1024), 256, 0, stream>>>(pval, pidx, prompts_h, rm_i, rm_t);

  // ---- QKV projections (q from fi/ft first 512 cols, lda=1024) ----
  {
    Ptrs8 p{};
    p.A[0] = fi; p.B[0] = in_w_i_h; p.bias[0] = img_in_b; p.D[0] = qkv_i;
    p.A[1] = ft; p.B[1] = in_w_t_h; p.bias[1] = txt_in_b; p.D[1] = qkv_t;
    gemm_nt<128, 128, 2, 2, 0, 0><<<dim3(16, 4, 2), 256, 0, stream>>>(p, 512, 1024, 512, 1536);
  }
  {
    Ptrs8 p{};
    p.A[0] = rm_i; p.B[0] = in_w_i_h + (size_t)512 * 512; p.bias[0] = img_in_b + 512; p.D[0] = qkv_i + 512;
    p.A[1] = rm_t; p.B[1] = in_w_t_h + (size_t)512 * 512; p.bias[1] = txt_in_b + 512; p.D[1] = qkv_t + 512;
    gemm_nt<128, 128, 2, 2, 0, 0><<<dim3(16, 8, 2), 256, 0, stream>>>(p, 512, 512, 512, 1536);
  }
  transpose_vp<<<dim3(32, 8, 2), 256, 0, stream>>>(qkv_i, qkv_t, vpT_i, vpT_t);

  // ---- attention per modality (scores buffer shared) ----
  for (int mod = 0; mod < 2; ++mod) {
    F16* qkv = mod ? qkv_t : qkv_i;
    F16* vpT = mod ? vpT_t : vpT_i;
    F16* attn = mod ? attn_t : attn_i;
    {
      Ptrs8 p{};
      for (int h = 0; h < 8; ++h) {
        p.A[h] = qkv + h * 64;
        p.B[h] = qkv + 512 + h * 64;
        p.bias[h] = nullptr;
        p.D[h] = scores + (size_t)h * 2048 * 2048;
      }
      gemm_nt<128, 128, 2, 2, 0, 0><<<dim3(16, 16, 8), 256, 0, stream>>>(p, 64, 1536, 1536, 2048);
    }
    softmax_rows<<<dim3(16384), 256, 0, stream>>>(scores);
    {
      Ptrs8 p{};
      for (int h = 0; h < 8; ++h) {
        p.A[h] = scores + (size_t)h * 2048 * 2048;
        p.B[h] = vpT + (size_t)h * 64 * 2048;
        p.bias[h] = nullptr;
        p.D[h] = attn + h * 64;
      }
      gemm_nt<64, 64, 2, 2, 0, 0><<<dim3(32, 1, 8), 256, 0, stream>>>(p, 2048, 2048, 2048, 512);
    }
  }
  {
    Ptrs8 p{};
    p.A[0] = attn_i; p.B[0] = out_w_i_h; p.bias[0] = img_out_b; p.D[0] = fi + 512;
    p.A[1] = attn_t; p.B[1] = out_w_t_h; p.bias[1] = txt_out_b; p.D[1] = ft + 512;
    gemm_nt<128, 128, 2, 2, 0, 0><<<dim3(16, 4, 2), 256, 0, stream>>>(p, 512, 512, 512, 1024);
  }

  // ---- MLPs, weight-grouped order: z0=(fi,img)->image_hash z2=(ft,img)->distill_i
  //                                  z1=(ft,txt)->text_hash  z3=(fi,txt)->distill_t
  const int zlist[4] = {0, 2, 1, 3};  // pairs share a weight set (img, img, txt, txt)
  const F16* mlpA[4] = {fi, ft, ft, fi};
  const float* mb1[4] = {img_b1, txt_b1, img_b1, txt_b1};
  const float* mb2[4] = {img_b2, txt_b2, img_b2, txt_b2};
  const float* mbc[4] = {img_bc, txt_bc, img_bc, txt_bc};
  const F16* mW1[4] = {W1_i, W1_t, W1_i, W1_t};
  const F16* mWc[4] = {Wc_i, Wc_t, Wc_i, Wc_t};

  for (int b0 = 0; b0 < 4; b0 += zb) {
    F16* h1 = scores;                                                   // zb*16MB
    F16* h2 = h2full ? h2full : scores + (size_t)zb * 2048 * 4096;      // tight: upper half
    {
      Ptrs8 p{};
      for (int q = 0; q < zb; ++q) {
        int z = zlist[b0 + q];
        p.A[q] = mlpA[z]; p.B[q] = mW1[z]; p.bias[q] = mb1[z];
        p.D[q] = h1 + (size_t)q * 2048 * 4096;
      }
      gemm_nt<128, 128, 2, 2, 1, 0><<<dim3(16, 32, zb), 256, 0, stream>>>(p, 1024, 1024, 1024, 4096);
    }
    {
      // W2 for this pass: tier 1/2 -> resident copies; tier 3 -> cast into shared now.
      const F16* w2a = nullptr, *w2b = nullptr;
      if (W2_i) {
        w2a = (zlist[b0] == 0 || zlist[b0] == 2) ? W2_i : W2_t;
        w2b = (zb == 4) ? nullptr : w2a;  // zb==4 handled per-q below
      } else {
        const float* srcw2 = (zlist[b0] == 0 || zlist[b0] == 2) ? img_W2 : txt_W2;
        cast_one<<<dim3(8192), 256, 0, stream>>>(srcw2, W2_shared);
        w2a = W2_shared;
      }
      Ptrs8 p{};
      for (int q = 0; q < zb; ++q) {
        int z = zlist[b0 + q];
        const F16* wz = W2_i ? ((z == 0 || z == 2) ? W2_i : W2_t) : w2a;
        p.A[q] = h1 + (size_t)q * 2048 * 4096; p.B[q] = wz; p.bias[q] = mb2[z];
        p.D[q] = h2 + (size_t)q * 2048 * 4096;
      }
      (void)w2b;
      gemm_nt<128, 128, 2, 2, 1, 0><<<dim3(16, 32, zb), 256, 0, stream>>>(p, 4096, 4096, 4096, 4096);
    }
    {
      Ptrs8 p{};
      for (int q = 0; q < zb; ++q) {
        int z = zlist[b0 + q];
        p.A[q] = h2 + (size_t)q * 2048 * 4096; p.B[q] = mWc[z]; p.bias[q] = mbc[z];
        p.D[q] = out + (size_t)z * 2048 * 64;
      }
      gemm_nt<64, 64, 2, 2, 0, 1, 1><<<dim3(32, 1, zb), 256, 0, stream>>>(p, 4096, 4096, 4096, 64);
    }
  }
}